// Round 4
// baseline (179.252 us; speedup 1.0000x reference)
//
#include <hip/hip_runtime.h>
#include <hip/hip_bf16.h>

// Problem constants
#define BS 16
#define NN 512
#define DD 256
#define RR 2
#define M_TOT (BS * NN)   // 8192 rows
#define KCAT 768          // concat K = DD * (1 + RR)

typedef __attribute__((ext_vector_type(8))) short short8;
typedef __attribute__((ext_vector_type(4))) float f32x4;

static __device__ __forceinline__ ushort f2bf(float f) {
  __hip_bfloat16 h = __float2bfloat16(f);
  return *reinterpret_cast<ushort*>(&h);
}

// ---------------------------------------------------------------------------
// K0: transposed packed masks bitsT[r][b][j][w] (w = i/64, bit = i%64)
//   mask0 (punct): punct==1 && aug!=1 ; mask1 (aug): aug==1
// ---------------------------------------------------------------------------
__global__ __launch_bounds__(256) void masks_kernel(
    const int* __restrict__ aug, const int* __restrict__ punct,
    unsigned long long* __restrict__ bitsT) {
  int j = blockIdx.x * 256 + threadIdx.x;
  int w = blockIdx.y;
  int b = blockIdx.z;
  long base = ((long)(b * NN + w * 64)) * NN + j;
  unsigned long long m0 = 0ull, m1 = 0ull;
#pragma unroll 16
  for (int k = 0; k < 64; ++k) {
    int a = aug[base + (long)k * NN];
    int p = punct[base + (long)k * NN];
    unsigned long long isa = (unsigned long long)(a == 1);
    unsigned long long isp = (unsigned long long)((p == 1) & (a != 1));
    m1 |= isa << k;
    m0 |= isp << k;
  }
  bitsT[((0 * BS + b) * NN + j) * 8 + w] = m0;
  bitsT[((1 * BS + b) * NN + j) * 8 + w] = m1;
}

// ---------------------------------------------------------------------------
// K0c: expand bits -> exact bf16 0/1 matrix MT[r][b][j][i]; fused inv_deg.
// ---------------------------------------------------------------------------
__global__ __launch_bounds__(256) void mt_kernel(
    const unsigned long long* __restrict__ bitsT, ushort* __restrict__ MT,
    float* __restrict__ inv_deg) {
  int j = blockIdx.x, b = blockIdx.y;
  __shared__ unsigned long long words[2][8];
  int t = threadIdx.x;
  if (t < 16)
    words[t >> 3][t & 7] = bitsT[((t >> 3) * BS + b) * NN * 8 + j * 8 + (t & 7)];
  __syncthreads();
  if (t < 2) {
    int s = 0;
#pragma unroll
    for (int w = 0; w < 8; ++w) s += __popcll(words[t][w]);
    if (s < 1) s = 1;
    inv_deg[(t * BS + b) * NN + j] = 1.0f / (float)s;
  }
  int i0 = t * 2;
  int w = i0 >> 6;
#pragma unroll
  for (int r = 0; r < 2; ++r) {
    unsigned long long v = words[r][w] >> (i0 & 63);
    unsigned int packed = ((v & 1) ? 0x3F80u : 0u) | ((v & 2) ? 0x3F800000u : 0u);
    unsigned int* row = reinterpret_cast<unsigned int*>(
        MT + ((size_t)((r * BS + b) * NN + j)) * NN);
    row[t] = packed;
  }
}

// ---------------------------------------------------------------------------
// x prep (fused): x fp32 [b][i][d] -> Abig1 slice0 (bf16, stride 768)
//                              and -> xT [b][d][i] (bf16)
// ---------------------------------------------------------------------------
__global__ void xprep_kernel(const float* __restrict__ x,
                             ushort* __restrict__ Abig1,
                             ushort* __restrict__ xT) {
  __shared__ float tile[32][33];
  int i0 = blockIdx.x * 32, d0 = blockIdx.y * 32, b = blockIdx.z;
  int tx = threadIdx.x, ty = threadIdx.y;
#pragma unroll
  for (int q = 0; q < 4; ++q) {
    int il = ty + q * 8;
    tile[il][tx] = x[((long)(b * NN + i0 + il)) * DD + d0 + tx];
  }
  __syncthreads();
#pragma unroll
  for (int q = 0; q < 4; ++q) {
    int il = ty + q * 8;
    Abig1[(size_t)(b * NN + i0 + il) * KCAT + d0 + tx] = f2bf(tile[il][tx]);
  }
#pragma unroll
  for (int q = 0; q < 4; ++q) {
    int dl = ty + q * 8;
    xT[((size_t)(b * DD + d0 + dl)) * NN + i0 + tx] = f2bf(tile[tx][dl]);
  }
}

// ---------------------------------------------------------------------------
// transpose h: bf16 [m=b*512+j][768] slice0 -> bf16 hT [b][d][j]
// ---------------------------------------------------------------------------
__global__ void transpose_h_kernel(const ushort* __restrict__ A2,
                                   ushort* __restrict__ hT) {
  __shared__ ushort tile[32][33];
  int i0 = blockIdx.x * 32, d0 = blockIdx.y * 32, b = blockIdx.z;
  int tx = threadIdx.x, ty = threadIdx.y;
#pragma unroll
  for (int q = 0; q < 4; ++q) {
    int il = ty + q * 8;
    tile[il][tx] = A2[((long)(b * NN + i0 + il)) * KCAT + d0 + tx];
  }
  __syncthreads();
#pragma unroll
  for (int q = 0; q < 4; ++q) {
    int dl = ty + q * 8;
    hT[((long)(b * DD + d0 + dl)) * NN + i0 + tx] = tile[tx][dl];
  }
}

// ---------------------------------------------------------------------------
// WcatT build for BOTH layers
// ---------------------------------------------------------------------------
__global__ void wcat_kernel(const float* __restrict__ wroot1,
                            const float* __restrict__ wrel1,
                            const float* __restrict__ wroot2,
                            const float* __restrict__ wrel2,
                            ushort* __restrict__ W1, ushort* __restrict__ W2) {
  __shared__ float tile[32][33];
  int z = blockIdx.z;
  int layer = z / 3, s = z % 3;
  const float* root = layer ? wroot2 : wroot1;
  const float* rel = layer ? wrel2 : wrel1;
  ushort* dst = layer ? W2 : W1;
  const float* src = (s == 0) ? root : (rel + (size_t)(s - 1) * DD * DD);
  int d0 = blockIdx.x * 32, e0 = blockIdx.y * 32;
  int tx = threadIdx.x, ty = threadIdx.y;
#pragma unroll
  for (int q = 0; q < 4; ++q) {
    int dl = ty + q * 8;
    tile[dl][tx] = src[((long)(d0 + dl)) * DD + e0 + tx];
  }
  __syncthreads();
#pragma unroll
  for (int q = 0; q < 4; ++q) {
    int el = ty + q * 8;
    dst[((size_t)(e0 + el)) * KCAT + s * 256 + d0 + tx] = f2bf(tile[tx][el]);
  }
}

// ---------------------------------------------------------------------------
// agg GEMM: agg[r,b][j][d] = inv_deg * sum_i MT[r,b][j][i] * xT[b][d][i]
// 128Mx64N tile, BK=32, 2-deep reg-staged LDS pipeline.
// grid (4 d-tiles, 4 j-tiles, 32 rb) = 512 blocks, 4 waves (64x32 each).
// ---------------------------------------------------------------------------
__global__ __launch_bounds__(256) void agg_gemm_kernel(
    const ushort* __restrict__ MT, const ushort* __restrict__ xT,
    const float* __restrict__ inv_deg, ushort* __restrict__ Abig) {
  __shared__ __align__(16) ushort As[2][128][40];
  __shared__ __align__(16) ushort Bs[2][64][40];
  int t = threadIdx.x;
  int rb = blockIdx.z;
  int r = rb >> 4, b = rb & 15;
  int m_base = blockIdx.y * 128;  // j
  int n_base = blockIdx.x * 64;   // d
  int srow = t >> 2, scol = (t & 3) * 8;

  const ushort* Ag0 = MT + ((size_t)((r * BS + b) * NN + m_base + srow)) * NN + scol;
  const ushort* Ag1 = Ag0 + (size_t)64 * NN;
  const ushort* Bg = xT + ((size_t)(b * DD + n_base + srow)) * NN + scol;

  int wave = t >> 6, lane = t & 63;
  int wm = wave >> 1, wn = wave & 1;
  int fr = lane & 15, fq = lane >> 4;

  f32x4 acc[4][2];
#pragma unroll
  for (int i = 0; i < 4; ++i)
#pragma unroll
    for (int jj = 0; jj < 2; ++jj) acc[i][jj] = (f32x4)(0.0f);

  const int NT = NN / 32;  // 16
  // 2-deep pipeline: set A = data for kt+2, set B = data for kt+1
  int4 pa0A, pa1A, pbA, pa0B, pa1B, pbB;
  pa0A = *reinterpret_cast<const int4*>(Ag0);
  pa1A = *reinterpret_cast<const int4*>(Ag1);
  pbA  = *reinterpret_cast<const int4*>(Bg);
  pa0B = *reinterpret_cast<const int4*>(Ag0 + 32);
  pa1B = *reinterpret_cast<const int4*>(Ag1 + 32);
  pbB  = *reinterpret_cast<const int4*>(Bg + 32);
  *reinterpret_cast<int4*>(&As[0][srow][scol]) = pa0A;
  *reinterpret_cast<int4*>(&As[0][64 + srow][scol]) = pa1A;
  *reinterpret_cast<int4*>(&Bs[0][srow][scol]) = pbA;
  __syncthreads();

#pragma unroll 2
  for (int kt = 0; kt < NT; ++kt) {
    if (kt + 2 < NT) {
      pa0A = *reinterpret_cast<const int4*>(Ag0 + (kt + 2) * 32);
      pa1A = *reinterpret_cast<const int4*>(Ag1 + (kt + 2) * 32);
      pbA  = *reinterpret_cast<const int4*>(Bg + (kt + 2) * 32);
    }
    int cur = kt & 1;
    short8 a0 = *reinterpret_cast<const short8*>(&As[cur][wm * 64 + fr][fq * 8]);
    short8 a1 = *reinterpret_cast<const short8*>(&As[cur][wm * 64 + 16 + fr][fq * 8]);
    short8 a2 = *reinterpret_cast<const short8*>(&As[cur][wm * 64 + 32 + fr][fq * 8]);
    short8 a3 = *reinterpret_cast<const short8*>(&As[cur][wm * 64 + 48 + fr][fq * 8]);
    short8 b0 = *reinterpret_cast<const short8*>(&Bs[cur][wn * 32 + fr][fq * 8]);
    short8 b1 = *reinterpret_cast<const short8*>(&Bs[cur][wn * 32 + 16 + fr][fq * 8]);
    acc[0][0] = __builtin_amdgcn_mfma_f32_16x16x32_bf16(a0, b0, acc[0][0], 0, 0, 0);
    acc[0][1] = __builtin_amdgcn_mfma_f32_16x16x32_bf16(a0, b1, acc[0][1], 0, 0, 0);
    acc[1][0] = __builtin_amdgcn_mfma_f32_16x16x32_bf16(a1, b0, acc[1][0], 0, 0, 0);
    acc[1][1] = __builtin_amdgcn_mfma_f32_16x16x32_bf16(a1, b1, acc[1][1], 0, 0, 0);
    acc[2][0] = __builtin_amdgcn_mfma_f32_16x16x32_bf16(a2, b0, acc[2][0], 0, 0, 0);
    acc[2][1] = __builtin_amdgcn_mfma_f32_16x16x32_bf16(a2, b1, acc[2][1], 0, 0, 0);
    acc[3][0] = __builtin_amdgcn_mfma_f32_16x16x32_bf16(a3, b0, acc[3][0], 0, 0, 0);
    acc[3][1] = __builtin_amdgcn_mfma_f32_16x16x32_bf16(a3, b1, acc[3][1], 0, 0, 0);
    if (kt + 1 < NT) {
      int nxt = cur ^ 1;
      *reinterpret_cast<int4*>(&As[nxt][srow][scol]) = pa0B;
      *reinterpret_cast<int4*>(&As[nxt][64 + srow][scol]) = pa1B;
      *reinterpret_cast<int4*>(&Bs[nxt][srow][scol]) = pbB;
    }
    __syncthreads();
    pa0B = pa0A; pa1B = pa1A; pbB = pbA;
  }

  const float* idg = inv_deg + (r * BS + b) * NN + m_base;
#pragma unroll
  for (int mi = 0; mi < 4; ++mi) {
#pragma unroll
    for (int t4 = 0; t4 < 4; ++t4) {
      int jl = wm * 64 + mi * 16 + fq * 4 + t4;
      float idv = idg[jl];
      size_t rowoff =
          (size_t)(b * NN + m_base + jl) * KCAT + 256 + r * 256 + n_base;
#pragma unroll
      for (int ni = 0; ni < 2; ++ni) {
        int d = wn * 32 + ni * 16 + fr;
        Abig[rowoff + d] = f2bf(acc[mi][ni][t4] * idv);
      }
    }
  }
}

// ---------------------------------------------------------------------------
// main GEMM: out[m][e] = elu(bias[e] + sum_k Abig[m][k] * WcatT[e][k])
// 64x64 tile, BK=32, 2-deep pipeline. grid (4, 128) = 512 blocks.
// ---------------------------------------------------------------------------
template <int MODE>
__global__ __launch_bounds__(256) void main_gemm_kernel(
    const ushort* __restrict__ A, const ushort* __restrict__ WcatT,
    const float* __restrict__ bias, ushort* __restrict__ hOut,
    float* __restrict__ fOut) {
  __shared__ __align__(16) ushort As[2][64][40];
  __shared__ __align__(16) ushort Bs[2][64][40];
  int t = threadIdx.x;
  int m_base = blockIdx.y * 64;
  int n_base = blockIdx.x * 64;
  int srow = t >> 2, scol = (t & 3) * 8;
  const ushort* Ag = A + (size_t)(m_base + srow) * KCAT + scol;
  const ushort* Bg = WcatT + (size_t)(n_base + srow) * KCAT + scol;

  int wave = t >> 6, lane = t & 63;
  int wm = wave >> 1, wn = wave & 1;
  int fr = lane & 15, fq = lane >> 4;

  f32x4 acc[2][2];
#pragma unroll
  for (int i = 0; i < 2; ++i)
#pragma unroll
    for (int jj = 0; jj < 2; ++jj) acc[i][jj] = (f32x4)(0.0f);

  const int NT = KCAT / 32;  // 24
  int4 paA, pbA, paB, pbB;
  paA = *reinterpret_cast<const int4*>(Ag);
  pbA = *reinterpret_cast<const int4*>(Bg);
  paB = *reinterpret_cast<const int4*>(Ag + 32);
  pbB = *reinterpret_cast<const int4*>(Bg + 32);
  *reinterpret_cast<int4*>(&As[0][srow][scol]) = paA;
  *reinterpret_cast<int4*>(&Bs[0][srow][scol]) = pbA;
  __syncthreads();

#pragma unroll 2
  for (int kt = 0; kt < NT; ++kt) {
    if (kt + 2 < NT) {
      paA = *reinterpret_cast<const int4*>(Ag + (kt + 2) * 32);
      pbA = *reinterpret_cast<const int4*>(Bg + (kt + 2) * 32);
    }
    int cur = kt & 1;
    short8 a0 = *reinterpret_cast<const short8*>(&As[cur][wm * 32 + fr][fq * 8]);
    short8 a1 = *reinterpret_cast<const short8*>(&As[cur][wm * 32 + 16 + fr][fq * 8]);
    short8 b0 = *reinterpret_cast<const short8*>(&Bs[cur][wn * 32 + fr][fq * 8]);
    short8 b1 = *reinterpret_cast<const short8*>(&Bs[cur][wn * 32 + 16 + fr][fq * 8]);
    acc[0][0] = __builtin_amdgcn_mfma_f32_16x16x32_bf16(a0, b0, acc[0][0], 0, 0, 0);
    acc[0][1] = __builtin_amdgcn_mfma_f32_16x16x32_bf16(a0, b1, acc[0][1], 0, 0, 0);
    acc[1][0] = __builtin_amdgcn_mfma_f32_16x16x32_bf16(a1, b0, acc[1][0], 0, 0, 0);
    acc[1][1] = __builtin_amdgcn_mfma_f32_16x16x32_bf16(a1, b1, acc[1][1], 0, 0, 0);
    if (kt + 1 < NT) {
      int nxt = cur ^ 1;
      *reinterpret_cast<int4*>(&As[nxt][srow][scol]) = paB;
      *reinterpret_cast<int4*>(&Bs[nxt][srow][scol]) = pbB;
    }
    __syncthreads();
    paB = paA; pbB = pbA;
  }

#pragma unroll
  for (int mi = 0; mi < 2; ++mi) {
#pragma unroll
    for (int t4 = 0; t4 < 4; ++t4) {
      int m = m_base + wm * 32 + mi * 16 + fq * 4 + t4;
#pragma unroll
      for (int ni = 0; ni < 2; ++ni) {
        int e = n_base + wn * 32 + ni * 16 + fr;
        float v = acc[mi][ni][t4] + bias[e];
        v = v > 0.0f ? v : expm1f(v);
        if (MODE == 0)
          hOut[(size_t)m * KCAT + e] = f2bf(v);
        else
          fOut[(size_t)m * DD + e] = v;
      }
    }
  }
}

extern "C" void kernel_launch(void* const* d_in, const int* in_sizes, int n_in,
                              void* d_out, int out_size, void* d_ws,
                              size_t ws_size, hipStream_t stream) {
  const float* x = (const float*)d_in[0];
  const float* w_rel1 = (const float*)d_in[1];
  const float* w_root1 = (const float*)d_in[2];
  const float* b1 = (const float*)d_in[3];
  const float* w_rel2 = (const float*)d_in[4];
  const float* w_root2 = (const float*)d_in[5];
  const float* b2 = (const float*)d_in[6];
  const int* aug = (const int*)d_in[7];
  const int* punct = (const int*)d_in[8];
  float* out = (float*)d_out;

  char* ws = (char*)d_ws;
  size_t off = 0;
  unsigned long long* bitsT = (unsigned long long*)(ws + off); off += (size_t)RR * BS * NN * 8 * 8;
  float* inv_deg = (float*)(ws + off);                         off += (size_t)RR * BS * NN * 4;
  ushort* MT = (ushort*)(ws + off);                            off += (size_t)RR * BS * NN * NN * 2;
  ushort* xT = (ushort*)(ws + off);                            off += (size_t)BS * DD * NN * 2;
  ushort* WcatT1 = (ushort*)(ws + off);                        off += (size_t)DD * KCAT * 2;
  ushort* WcatT2 = (ushort*)(ws + off);                        off += (size_t)DD * KCAT * 2;
  ushort* Abig1 = (ushort*)(ws + off);                         off += (size_t)M_TOT * KCAT * 2;
  ushort* Abig2 = (ushort*)(ws + off);                         off += (size_t)M_TOT * KCAT * 2;

  masks_kernel<<<dim3(2, 8, 16), 256, 0, stream>>>(aug, punct, bitsT);
  mt_kernel<<<dim3(NN, BS), 256, 0, stream>>>(bitsT, MT, inv_deg);

  xprep_kernel<<<dim3(16, 8, 16), dim3(32, 8), 0, stream>>>(x, Abig1, xT);
  wcat_kernel<<<dim3(8, 8, 6), dim3(32, 8), 0, stream>>>(w_root1, w_rel1,
                                                         w_root2, w_rel2,
                                                         WcatT1, WcatT2);

  // layer 1
  agg_gemm_kernel<<<dim3(4, 4, 32), 256, 0, stream>>>(MT, xT, inv_deg, Abig1);
  main_gemm_kernel<0><<<dim3(4, 128), 256, 0, stream>>>(Abig1, WcatT1, b1,
                                                        Abig2, nullptr);

  // layer 2
  transpose_h_kernel<<<dim3(16, 8, 16), dim3(32, 8), 0, stream>>>(Abig2, xT);
  agg_gemm_kernel<<<dim3(4, 4, 32), 256, 0, stream>>>(MT, xT, inv_deg, Abig2);
  main_gemm_kernel<1><<<dim3(4, 128), 256, 0, stream>>>(Abig2, WcatT2, b2,
                                                        nullptr, out);
}

// Round 6
// 176.613 us; speedup vs baseline: 1.0149x; 1.0149x over previous
//
#include <hip/hip_runtime.h>
#include <hip/hip_bf16.h>

// Problem constants
#define BS 16
#define NN 512
#define DD 256
#define RR 2
#define M_TOT (BS * NN)   // 8192 rows
#define KCAT 768          // concat K = DD * (1 + RR)

typedef __attribute__((ext_vector_type(8))) short short8;
typedef __attribute__((ext_vector_type(4))) float f32x4;

static __device__ __forceinline__ ushort f2bf(float f) {
  __hip_bfloat16 h = __float2bfloat16(f);
  return *reinterpret_cast<ushort*>(&h);
}
static __device__ __forceinline__ uint pack2bf(float a, float b) {
  return (uint)f2bf(a) | ((uint)f2bf(b) << 16);
}

// ---------------------------------------------------------------------------
// K0: transposed packed masks bitsT[r][b][j][w] (w = i/64, bit = i%64)
// ---------------------------------------------------------------------------
__global__ __launch_bounds__(256) void masks_kernel(
    const int* __restrict__ aug, const int* __restrict__ punct,
    unsigned long long* __restrict__ bitsT) {
  int j = blockIdx.x * 256 + threadIdx.x;
  int w = blockIdx.y;
  int b = blockIdx.z;
  long base = ((long)(b * NN + w * 64)) * NN + j;
  unsigned long long m0 = 0ull, m1 = 0ull;
#pragma unroll 16
  for (int k = 0; k < 64; ++k) {
    int a = aug[base + (long)k * NN];
    int p = punct[base + (long)k * NN];
    unsigned long long isa = (unsigned long long)(a == 1);
    unsigned long long isp = (unsigned long long)((p == 1) & (a != 1));
    m1 |= isa << k;
    m0 |= isp << k;
  }
  bitsT[((0 * BS + b) * NN + j) * 8 + w] = m0;
  bitsT[((1 * BS + b) * NN + j) * 8 + w] = m1;
}

// ---------------------------------------------------------------------------
// K0c: bits -> exact bf16 0/1 matrix MT[r][b][j][i]; fused inv_deg.
// ---------------------------------------------------------------------------
__global__ __launch_bounds__(256) void mt_kernel(
    const unsigned long long* __restrict__ bitsT, ushort* __restrict__ MT,
    float* __restrict__ inv_deg) {
  int j = blockIdx.x, b = blockIdx.y;
  __shared__ unsigned long long words[2][8];
  int t = threadIdx.x;
  if (t < 16)
    words[t >> 3][t & 7] = bitsT[((t >> 3) * BS + b) * NN * 8 + j * 8 + (t & 7)];
  __syncthreads();
  if (t < 2) {
    int s = 0;
#pragma unroll
    for (int w = 0; w < 8; ++w) s += __popcll(words[t][w]);
    if (s < 1) s = 1;
    inv_deg[(t * BS + b) * NN + j] = 1.0f / (float)s;
  }
  int i0 = t * 2;
  int w = i0 >> 6;
#pragma unroll
  for (int r = 0; r < 2; ++r) {
    unsigned long long v = words[r][w] >> (i0 & 63);
    unsigned int packed = ((v & 1) ? 0x3F80u : 0u) | ((v & 2) ? 0x3F800000u : 0u);
    unsigned int* row = reinterpret_cast<unsigned int*>(
        MT + ((size_t)((r * BS + b) * NN + j)) * NN);
    row[t] = packed;
  }
}

// ---------------------------------------------------------------------------
// x prep: x fp32 [b][i][d] -> xbf [m][256] bf16  and  xT [b][d][i] bf16
// ---------------------------------------------------------------------------
__global__ void xprep_kernel(const float* __restrict__ x,
                             ushort* __restrict__ xbf,
                             ushort* __restrict__ xT) {
  __shared__ float tile[32][33];
  int i0 = blockIdx.x * 32, d0 = blockIdx.y * 32, b = blockIdx.z;
  int tx = threadIdx.x, ty = threadIdx.y;
#pragma unroll
  for (int q = 0; q < 4; ++q) {
    int il = ty + q * 8;
    tile[il][tx] = x[((long)(b * NN + i0 + il)) * DD + d0 + tx];
  }
  __syncthreads();
#pragma unroll
  for (int q = 0; q < 4; ++q) {
    int il = ty + q * 8;
    xbf[(size_t)(b * NN + i0 + il) * DD + d0 + tx] = f2bf(tile[il][tx]);
  }
#pragma unroll
  for (int q = 0; q < 4; ++q) {
    int dl = ty + q * 8;
    xT[((size_t)(b * DD + d0 + dl)) * NN + i0 + tx] = f2bf(tile[tx][dl]);
  }
}

// ---------------------------------------------------------------------------
// WcatT build for BOTH layers: WcatT[e][s*256+d] = W_s[d][e]
// ---------------------------------------------------------------------------
__global__ void wcat_kernel(const float* __restrict__ wroot1,
                            const float* __restrict__ wrel1,
                            const float* __restrict__ wroot2,
                            const float* __restrict__ wrel2,
                            ushort* __restrict__ W1, ushort* __restrict__ W2) {
  __shared__ float tile[32][33];
  int z = blockIdx.z;
  int layer = z / 3, s = z % 3;
  const float* root = layer ? wroot2 : wroot1;
  const float* rel = layer ? wrel2 : wrel1;
  ushort* dst = layer ? W2 : W1;
  const float* src = (s == 0) ? root : (rel + (size_t)(s - 1) * DD * DD);
  int d0 = blockIdx.x * 32, e0 = blockIdx.y * 32;
  int tx = threadIdx.x, ty = threadIdx.y;
#pragma unroll
  for (int q = 0; q < 4; ++q) {
    int dl = ty + q * 8;
    tile[dl][tx] = src[((long)(d0 + dl)) * DD + e0 + tx];
  }
  __syncthreads();
#pragma unroll
  for (int q = 0; q < 4; ++q) {
    int el = ty + q * 8;
    dst[((size_t)(e0 + el)) * KCAT + s * 256 + d0 + tx] = f2bf(tile[tx][el]);
  }
}

// ---------------------------------------------------------------------------
// Fused layer kernel. Block = (jt, b): 32 output rows (j0..j0+31) x 256 cols.
// Phase A (no barriers): agg^T[d][j] = sum_i xT[b][d][i] * MT[r][b][j][i]
//   via direct-global b128 fragment loads (xT slab + MT slice are L2-hot).
//   Scaled by inv_deg, packed bf16 into LDS Acat[j][256+r*256+d].
// Acat x-part staged from xbf at start. One barrier. Phase B (no barriers):
//   out[j][e] = sum_k Acat[j][k] * WT[e][k]  (WT rows direct-global, L2-hot).
// LAYER 0: writes hbf rows + hT (LDS-transposed, Acat aliased). LAYER 1: f32 out.
// ---------------------------------------------------------------------------
template <int LAYER>
__global__ __launch_bounds__(256) void layer_kernel(
    const ushort* __restrict__ xbf, const ushort* __restrict__ xT,
    const ushort* __restrict__ MT, const float* __restrict__ inv_deg,
    const ushort* __restrict__ WT, const float* __restrict__ bias,
    ushort* __restrict__ hbf, ushort* __restrict__ hT,
    float* __restrict__ fOut) {
  // Acat: [32][776] ushort (49664 B). Pad 776 -> conflict-free b128 row reads
  // ((byte/16)%8 = (j + fq + c)%8, distinct within 8-lane groups).
  __shared__ __align__(16) char smem[32 * 776 * 2];
  ushort(*Acat)[776] = reinterpret_cast<ushort(*)[776]>(smem);
  ushort(*LT)[40] = reinterpret_cast<ushort(*)[40]>(smem);  // layer0 reuse

  int t = threadIdx.x;
  int w = t >> 6, lane = t & 63;
  int fr = lane & 15, fq = lane >> 4;
  int jt = blockIdx.x, b = blockIdx.y;
  int j0 = jt * 32;

  // ---- stage x rows into Acat cols 0..255 (thread: row t>>3, 32 cols) ----
  {
    int jr = t >> 3, c0 = (t & 7) * 32;
    const ushort* xr = xbf + (size_t)(b * NN + j0 + jr) * DD + c0;
#pragma unroll
    for (int q = 0; q < 4; ++q) {
      int4 v = *reinterpret_cast<const int4*>(xr + q * 8);
      *reinterpret_cast<int4*>(&Acat[jr][c0 + q * 8]) = v;
    }
  }

  // ---- inv_deg for this lane's j columns ----
  float idv[2][2];
#pragma unroll
  for (int r = 0; r < 2; ++r)
#pragma unroll
    for (int jf = 0; jf < 2; ++jf)
      idv[r][jf] = inv_deg[(r * BS + b) * NN + j0 + jf * 16 + fr];

  // ---- Phase A: agg GEMM, direct-global fragments, no barriers ----
  const ushort* Arow[4];
#pragma unroll
  for (int df = 0; df < 4; ++df)
    Arow[df] = xT + ((size_t)b * DD + w * 64 + df * 16 + fr) * NN + fq * 8;
  const ushort* Brow[2][2];
#pragma unroll
  for (int r = 0; r < 2; ++r)
#pragma unroll
    for (int jf = 0; jf < 2; ++jf)
      Brow[r][jf] =
          MT + ((size_t)((r * BS + b) * NN) + j0 + jf * 16 + fr) * NN + fq * 8;

  f32x4 accA[2][4][2];
#pragma unroll
  for (int r = 0; r < 2; ++r)
#pragma unroll
    for (int df = 0; df < 4; ++df)
#pragma unroll
      for (int jf = 0; jf < 2; ++jf) accA[r][df][jf] = (f32x4)(0.0f);

#pragma unroll 2
  for (int kt = 0; kt < NN / 32; ++kt) {
    int k0 = kt * 32;
    short8 af[4], bf0[2], bf1[2];
#pragma unroll
    for (int df = 0; df < 4; ++df)
      af[df] = *reinterpret_cast<const short8*>(Arow[df] + k0);
#pragma unroll
    for (int jf = 0; jf < 2; ++jf) {
      bf0[jf] = *reinterpret_cast<const short8*>(Brow[0][jf] + k0);
      bf1[jf] = *reinterpret_cast<const short8*>(Brow[1][jf] + k0);
    }
#pragma unroll
    for (int df = 0; df < 4; ++df)
#pragma unroll
      for (int jf = 0; jf < 2; ++jf) {
        accA[0][df][jf] = __builtin_amdgcn_mfma_f32_16x16x32_bf16(
            af[df], bf0[jf], accA[0][df][jf], 0, 0, 0);
        accA[1][df][jf] = __builtin_amdgcn_mfma_f32_16x16x32_bf16(
            af[df], bf1[jf], accA[1][df][jf], 0, 0, 0);
      }
  }

  // ---- scale + pack agg into Acat[j][256 + r*256 + d] ----
#pragma unroll
  for (int r = 0; r < 2; ++r)
#pragma unroll
    for (int df = 0; df < 4; ++df)
#pragma unroll
      for (int jf = 0; jf < 2; ++jf) {
        float s = idv[r][jf];
        uint2 pk;
        pk.x = pack2bf(accA[r][df][jf][0] * s, accA[r][df][jf][1] * s);
        pk.y = pack2bf(accA[r][df][jf][2] * s, accA[r][df][jf][3] * s);
        int row = jf * 16 + fr;
        int col = 256 + r * 256 + w * 64 + df * 16 + fq * 4;
        *reinterpret_cast<uint2*>(&Acat[row][col]) = pk;
      }
  __syncthreads();

  // ---- Phase B: out[j][e] = Acat[j][:] . WT[e][:], WT direct-global ----
  const ushort* Wrow[4];
#pragma unroll
  for (int ef = 0; ef < 4; ++ef)
    Wrow[ef] = WT + (size_t)(w * 64 + ef * 16 + fr) * KCAT + fq * 8;

  f32x4 accB[2][4];
#pragma unroll
  for (int jf = 0; jf < 2; ++jf)
#pragma unroll
    for (int ef = 0; ef < 4; ++ef) accB[jf][ef] = (f32x4)(0.0f);

#pragma unroll 2
  for (int kt = 0; kt < KCAT / 32; ++kt) {
    int k0 = kt * 32;
    short8 aa[2], bb[4];
#pragma unroll
    for (int jf = 0; jf < 2; ++jf)
      aa[jf] = *reinterpret_cast<const short8*>(&Acat[jf * 16 + fr][k0 + fq * 8]);
#pragma unroll
    for (int ef = 0; ef < 4; ++ef)
      bb[ef] = *reinterpret_cast<const short8*>(Wrow[ef] + k0);
#pragma unroll
    for (int jf = 0; jf < 2; ++jf)
#pragma unroll
      for (int ef = 0; ef < 4; ++ef)
        accB[jf][ef] = __builtin_amdgcn_mfma_f32_16x16x32_bf16(
            aa[jf], bb[ef], accB[jf][ef], 0, 0, 0);
  }

  float bsv[4];
#pragma unroll
  for (int ef = 0; ef < 4; ++ef) bsv[ef] = bias[w * 64 + ef * 16 + fr];

  if (LAYER == 1) {
#pragma unroll
    for (int jf = 0; jf < 2; ++jf)
#pragma unroll
      for (int ef = 0; ef < 4; ++ef)
#pragma unroll
        for (int t4 = 0; t4 < 4; ++t4) {
          int m = b * NN + j0 + jf * 16 + fq * 4 + t4;
          int e = w * 64 + ef * 16 + fr;
          float v = accB[jf][ef][t4] + bsv[ef];
          v = v > 0.0f ? v : expm1f(v);
          fOut[(size_t)m * DD + e] = v;
        }
  } else {
    // compute h (bf16), write rows, and stash packed values for transpose
    uint2 pk[2][4];
#pragma unroll
    for (int jf = 0; jf < 2; ++jf)
#pragma unroll
      for (int ef = 0; ef < 4; ++ef) {
        float v0 = accB[jf][ef][0] + bsv[ef];
        float v1 = accB[jf][ef][1] + bsv[ef];
        float v2 = accB[jf][ef][2] + bsv[ef];
        float v3 = accB[jf][ef][3] + bsv[ef];
        v0 = v0 > 0.0f ? v0 : expm1f(v0);
        v1 = v1 > 0.0f ? v1 : expm1f(v1);
        v2 = v2 > 0.0f ? v2 : expm1f(v2);
        v3 = v3 > 0.0f ? v3 : expm1f(v3);
        int e = w * 64 + ef * 16 + fr;
        ushort u0 = f2bf(v0), u1 = f2bf(v1), u2 = f2bf(v2), u3 = f2bf(v3);
        hbf[(size_t)(b * NN + j0 + jf * 16 + fq * 4 + 0) * DD + e] = u0;
        hbf[(size_t)(b * NN + j0 + jf * 16 + fq * 4 + 1) * DD + e] = u1;
        hbf[(size_t)(b * NN + j0 + jf * 16 + fq * 4 + 2) * DD + e] = u2;
        hbf[(size_t)(b * NN + j0 + jf * 16 + fq * 4 + 3) * DD + e] = u3;
        pk[jf][ef].x = (uint)u0 | ((uint)u1 << 16);
        pk[jf][ef].y = (uint)u2 | ((uint)u3 << 16);
      }
    __syncthreads();  // all Acat reads done; safe to alias as LT
#pragma unroll
    for (int jf = 0; jf < 2; ++jf)
#pragma unroll
      for (int ef = 0; ef < 4; ++ef) {
        int e = w * 64 + ef * 16 + fr;
        *reinterpret_cast<uint2*>(&LT[e][jf * 16 + fq * 4]) = pk[jf][ef];
      }
    __syncthreads();
    // hT[b][e][j0..j0+31]: thread t -> e = t, 4 x b128 row read, contiguous write
    {
      int e = t;
      ushort* dst = hT + ((size_t)b * DD + e) * NN + j0;
#pragma unroll
      for (int c = 0; c < 4; ++c) {
        int4 v = *reinterpret_cast<const int4*>(&LT[e][c * 8]);
        *reinterpret_cast<int4*>(dst + c * 8) = v;
      }
    }
  }
}

extern "C" void kernel_launch(void* const* d_in, const int* in_sizes, int n_in,
                              void* d_out, int out_size, void* d_ws,
                              size_t ws_size, hipStream_t stream) {
  const float* x = (const float*)d_in[0];
  const float* w_rel1 = (const float*)d_in[1];
  const float* w_root1 = (const float*)d_in[2];
  const float* b1 = (const float*)d_in[3];
  const float* w_rel2 = (const float*)d_in[4];
  const float* w_root2 = (const float*)d_in[5];
  const float* b2 = (const float*)d_in[6];
  const int* aug = (const int*)d_in[7];
  const int* punct = (const int*)d_in[8];
  float* out = (float*)d_out;

  char* ws = (char*)d_ws;
  size_t off = 0;
  unsigned long long* bitsT = (unsigned long long*)(ws + off); off += (size_t)RR * BS * NN * 8 * 8;
  float* inv_deg = (float*)(ws + off);                         off += (size_t)RR * BS * NN * 4;
  ushort* MT = (ushort*)(ws + off);                            off += (size_t)RR * BS * NN * NN * 2;
  ushort* xT = (ushort*)(ws + off);                            off += (size_t)BS * DD * NN * 2;
  ushort* hT = (ushort*)(ws + off);                            off += (size_t)BS * DD * NN * 2;
  ushort* xbf = (ushort*)(ws + off);                           off += (size_t)M_TOT * DD * 2;
  ushort* hbf = (ushort*)(ws + off);                           off += (size_t)M_TOT * DD * 2;
  ushort* WcatT1 = (ushort*)(ws + off);                        off += (size_t)DD * KCAT * 2;
  ushort* WcatT2 = (ushort*)(ws + off);                        off += (size_t)DD * KCAT * 2;

  masks_kernel<<<dim3(2, 8, 16), 256, 0, stream>>>(aug, punct, bitsT);
  mt_kernel<<<dim3(NN, BS), 256, 0, stream>>>(bitsT, MT, inv_deg);
  xprep_kernel<<<dim3(16, 8, 16), dim3(32, 8), 0, stream>>>(x, xbf, xT);
  wcat_kernel<<<dim3(8, 8, 6), dim3(32, 8), 0, stream>>>(w_root1, w_rel1,
                                                         w_root2, w_rel2,
                                                         WcatT1, WcatT2);

  layer_kernel<0><<<dim3(16, 16), 256, 0, stream>>>(
      xbf, xT, MT, inv_deg, WcatT1, b1, hbf, hT, nullptr);
  layer_kernel<1><<<dim3(16, 16), 256, 0, stream>>>(
      hbf, hT, MT, inv_deg, WcatT2, b2, nullptr, nullptr, out);
}

// Round 7
// 169.052 us; speedup vs baseline: 1.0603x; 1.0447x over previous
//
#include <hip/hip_runtime.h>
#include <hip/hip_bf16.h>

// Problem constants
#define BS 16
#define NN 512
#define DD 256
#define RR 2
#define M_TOT (BS * NN)   // 8192 rows
#define KCAT 768          // concat K = DD * (1 + RR)

typedef __attribute__((ext_vector_type(8))) short short8;
typedef __attribute__((ext_vector_type(4))) float f32x4;
typedef const __attribute__((address_space(1))) unsigned int as1u32;
typedef __attribute__((address_space(3))) unsigned int as3u32;

// async global->LDS, 16B per lane; LDS dest = wave-uniform base + lane*16
#define GLDS16(g, l) \
  __builtin_amdgcn_global_load_lds((as1u32*)(g), (as3u32*)(l), 16, 0, 0)

static __device__ __forceinline__ ushort f2bf(float f) {
  __hip_bfloat16 h = __float2bfloat16(f);
  return *reinterpret_cast<ushort*>(&h);
}

// ---------------------------------------------------------------------------
// K0: transposed packed masks bitsT[r][b][j][w] (w = i/64, bit = i%64)
// ---------------------------------------------------------------------------
__global__ __launch_bounds__(256) void masks_kernel(
    const int* __restrict__ aug, const int* __restrict__ punct,
    unsigned long long* __restrict__ bitsT) {
  int j = blockIdx.x * 256 + threadIdx.x;
  int w = blockIdx.y;
  int b = blockIdx.z;
  long base = ((long)(b * NN + w * 64)) * NN + j;
  unsigned long long m0 = 0ull, m1 = 0ull;
#pragma unroll 16
  for (int k = 0; k < 64; ++k) {
    int a = aug[base + (long)k * NN];
    int p = punct[base + (long)k * NN];
    unsigned long long isa = (unsigned long long)(a == 1);
    unsigned long long isp = (unsigned long long)((p == 1) & (a != 1));
    m1 |= isa << k;
    m0 |= isp << k;
  }
  bitsT[((0 * BS + b) * NN + j) * 8 + w] = m0;
  bitsT[((1 * BS + b) * NN + j) * 8 + w] = m1;
}

// ---------------------------------------------------------------------------
// K0c: bits -> exact bf16 0/1 matrix MT[r][b][j][i]; fused inv_deg.
// ---------------------------------------------------------------------------
__global__ __launch_bounds__(256) void mt_kernel(
    const unsigned long long* __restrict__ bitsT, ushort* __restrict__ MT,
    float* __restrict__ inv_deg) {
  int j = blockIdx.x, b = blockIdx.y;
  __shared__ unsigned long long words[2][8];
  int t = threadIdx.x;
  if (t < 16)
    words[t >> 3][t & 7] = bitsT[((t >> 3) * BS + b) * NN * 8 + j * 8 + (t & 7)];
  __syncthreads();
  if (t < 2) {
    int s = 0;
#pragma unroll
    for (int w = 0; w < 8; ++w) s += __popcll(words[t][w]);
    if (s < 1) s = 1;
    inv_deg[(t * BS + b) * NN + j] = 1.0f / (float)s;
  }
  int i0 = t * 2;
  int w = i0 >> 6;
#pragma unroll
  for (int r = 0; r < 2; ++r) {
    unsigned long long v = words[r][w] >> (i0 & 63);
    unsigned int packed = ((v & 1) ? 0x3F80u : 0u) | ((v & 2) ? 0x3F800000u : 0u);
    unsigned int* row = reinterpret_cast<unsigned int*>(
        MT + ((size_t)((r * BS + b) * NN + j)) * NN);
    row[t] = packed;
  }
}

// ---------------------------------------------------------------------------
// x prep: x fp32 [b][i][d] -> Abig1 slice0 (bf16, stride 768) and xT [b][d][i]
// ---------------------------------------------------------------------------
__global__ void xprep_kernel(const float* __restrict__ x,
                             ushort* __restrict__ Abig1,
                             ushort* __restrict__ xT) {
  __shared__ float tile[32][33];
  int i0 = blockIdx.x * 32, d0 = blockIdx.y * 32, b = blockIdx.z;
  int tx = threadIdx.x, ty = threadIdx.y;
#pragma unroll
  for (int q = 0; q < 4; ++q) {
    int il = ty + q * 8;
    tile[il][tx] = x[((long)(b * NN + i0 + il)) * DD + d0 + tx];
  }
  __syncthreads();
#pragma unroll
  for (int q = 0; q < 4; ++q) {
    int il = ty + q * 8;
    Abig1[(size_t)(b * NN + i0 + il) * KCAT + d0 + tx] = f2bf(tile[il][tx]);
  }
#pragma unroll
  for (int q = 0; q < 4; ++q) {
    int dl = ty + q * 8;
    xT[((size_t)(b * DD + d0 + dl)) * NN + i0 + tx] = f2bf(tile[tx][dl]);
  }
}

// ---------------------------------------------------------------------------
// WcatT build for BOTH layers: WcatT[e][s*256+d] = W_s[d][e]
// ---------------------------------------------------------------------------
__global__ void wcat_kernel(const float* __restrict__ wroot1,
                            const float* __restrict__ wrel1,
                            const float* __restrict__ wroot2,
                            const float* __restrict__ wrel2,
                            ushort* __restrict__ W1, ushort* __restrict__ W2) {
  __shared__ float tile[32][33];
  int z = blockIdx.z;
  int layer = z / 3, s = z % 3;
  const float* root = layer ? wroot2 : wroot1;
  const float* rel = layer ? wrel2 : wrel1;
  ushort* dst = layer ? W2 : W1;
  const float* src = (s == 0) ? root : (rel + (size_t)(s - 1) * DD * DD);
  int d0 = blockIdx.x * 32, e0 = blockIdx.y * 32;
  int tx = threadIdx.x, ty = threadIdx.y;
#pragma unroll
  for (int q = 0; q < 4; ++q) {
    int dl = ty + q * 8;
    tile[dl][tx] = src[((long)(d0 + dl)) * DD + e0 + tx];
  }
  __syncthreads();
#pragma unroll
  for (int q = 0; q < 4; ++q) {
    int el = ty + q * 8;
    dst[((size_t)(e0 + el)) * KCAT + s * 256 + d0 + tx] = f2bf(tile[tx][el]);
  }
}

// ---------------------------------------------------------------------------
// agg GEMM (m97-lite): agg[r,b][j][d] = inv_deg * sum_i MT[j][i] * xT[d][i]
// 128j x 64d tile, BK=32, dbuf LDS via global_load_lds, 1 barrier/kt.
// grid (4 d, 4 j, 32 rb) = 512 blocks (2/CU), 4 waves (64j x 32d each).
// Output -> Abig[(b*512+j)*768 + 256 + r*256 + d] (bf16).
// ---------------------------------------------------------------------------
__global__ __launch_bounds__(256) void agg_gemm_kernel(
    const ushort* __restrict__ MT, const ushort* __restrict__ xT,
    const float* __restrict__ inv_deg, ushort* __restrict__ Abig) {
  __shared__ __align__(16) ushort As[2][128 * 32];  // 16 KB
  __shared__ __align__(16) ushort Bs[2][64 * 32];   // 8 KB
  int t = threadIdx.x;
  int wv = t >> 6, ln = t & 63;
  int fr = ln & 15, fq = ln >> 4;
  int rb = blockIdx.z, r = rb >> 4, b = rb & 15;
  int m_base = blockIdx.y * 128, n_base = blockIdx.x * 64;

  const ushort* Ag = MT + ((size_t)((r * BS + b) * NN + m_base)) * NN;
  const ushort* Bg = xT + ((size_t)(b * DD + n_base)) * NN;
  int srow = ln >> 2;        // row within 16-row chunk
  int scol = (ln & 3) * 8;   // ushort col offset (16B granules)

  f32x4 acc[4][2];
#pragma unroll
  for (int i = 0; i < 4; ++i)
#pragma unroll
    for (int jj = 0; jj < 2; ++jj) acc[i][jj] = (f32x4)(0.0f);

  // prologue: stage kt=0 into buf 0
#pragma unroll
  for (int q = 0; q < 2; ++q) {
    int c = wv * 2 + q;
    GLDS16(Ag + (size_t)(c * 16 + srow) * NN + scol, &As[0][c * 512]);
  }
  GLDS16(Bg + (size_t)(wv * 16 + srow) * NN + scol, &Bs[0][wv * 512]);
  __syncthreads();

  const int NT = NN / 32;  // 16
  int wm = wv >> 1, wn = wv & 1;
#pragma unroll 1
  for (int kt = 0; kt < NT; ++kt) {
    int cur = kt & 1;
    if (kt + 1 < NT) {
      int k0 = (kt + 1) * 32;
#pragma unroll
      for (int q = 0; q < 2; ++q) {
        int c = wv * 2 + q;
        GLDS16(Ag + (size_t)(c * 16 + srow) * NN + k0 + scol,
               &As[cur ^ 1][c * 512]);
      }
      GLDS16(Bg + (size_t)(wv * 16 + srow) * NN + k0 + scol,
             &Bs[cur ^ 1][wv * 512]);
    }
    short8 a[4], bb[2];
#pragma unroll
    for (int mi = 0; mi < 4; ++mi)
      a[mi] = *reinterpret_cast<const short8*>(
          &As[cur][(wm * 64 + mi * 16 + fr) * 32 + fq * 8]);
#pragma unroll
    for (int ni = 0; ni < 2; ++ni)
      bb[ni] = *reinterpret_cast<const short8*>(
          &Bs[cur][(wn * 32 + ni * 16 + fr) * 32 + fq * 8]);
#pragma unroll
    for (int mi = 0; mi < 4; ++mi)
#pragma unroll
      for (int ni = 0; ni < 2; ++ni)
        acc[mi][ni] = __builtin_amdgcn_mfma_f32_16x16x32_bf16(
            a[mi], bb[ni], acc[mi][ni], 0, 0, 0);
    __syncthreads();  // waits vmcnt(0): next buf staged; cur reads done
  }

  const float* idg = inv_deg + (r * BS + b) * NN + m_base;
#pragma unroll
  for (int mi = 0; mi < 4; ++mi) {
#pragma unroll
    for (int t4 = 0; t4 < 4; ++t4) {
      int jl = wm * 64 + mi * 16 + fq * 4 + t4;
      float idv = idg[jl];
      size_t rowoff =
          (size_t)(b * NN + m_base + jl) * KCAT + 256 + r * 256 + n_base;
#pragma unroll
      for (int ni = 0; ni < 2; ++ni) {
        int d = wn * 32 + ni * 16 + fr;
        Abig[rowoff + d] = f2bf(acc[mi][ni][t4] * idv);
      }
    }
  }
}

// ---------------------------------------------------------------------------
// main GEMM (m97-lite): out[m][e] = elu(bias[e] + sum_k Abig[m][k]*WT[e][k])
// 64x64 tile, BK=32, dbuf LDS via global_load_lds. grid (4 e, 128 m) = 512.
// MODE 0: bf16 h -> hOut slice0 (stride 768) AND hT[b][e][j] (LDS transpose).
// MODE 1: fp32 out.
// ---------------------------------------------------------------------------
template <int MODE>
__global__ __launch_bounds__(256) void main_gemm_kernel(
    const ushort* __restrict__ A, const ushort* __restrict__ WT,
    const float* __restrict__ bias, ushort* __restrict__ hOut,
    ushort* __restrict__ hT, float* __restrict__ fOut) {
  __shared__ __align__(16) ushort As[2][64 * 32];  // 8 KB (also LT reuse)
  __shared__ __align__(16) ushort Bs[2][64 * 32];  // 8 KB
  int t = threadIdx.x;
  int wv = t >> 6, ln = t & 63;
  int fr = ln & 15, fq = ln >> 4;
  int m_base = blockIdx.y * 64, e_base = blockIdx.x * 64;

  const ushort* Ag = A + (size_t)m_base * KCAT;
  const ushort* Bg = WT + (size_t)e_base * KCAT;
  int srow = ln >> 2;
  int scol = (ln & 3) * 8;

  f32x4 acc[2][2];
#pragma unroll
  for (int i = 0; i < 2; ++i)
#pragma unroll
    for (int jj = 0; jj < 2; ++jj) acc[i][jj] = (f32x4)(0.0f);

  // prologue: stage kt=0 into buf 0 (1 chunk per wave per operand)
  GLDS16(Ag + (size_t)(wv * 16 + srow) * KCAT + scol, &As[0][wv * 512]);
  GLDS16(Bg + (size_t)(wv * 16 + srow) * KCAT + scol, &Bs[0][wv * 512]);
  __syncthreads();

  const int NT = KCAT / 32;  // 24
  int wm = wv >> 1, wn = wv & 1;
#pragma unroll 1
  for (int kt = 0; kt < NT; ++kt) {
    int cur = kt & 1;
    if (kt + 1 < NT) {
      int k0 = (kt + 1) * 32;
      GLDS16(Ag + (size_t)(wv * 16 + srow) * KCAT + k0 + scol,
             &As[cur ^ 1][wv * 512]);
      GLDS16(Bg + (size_t)(wv * 16 + srow) * KCAT + k0 + scol,
             &Bs[cur ^ 1][wv * 512]);
    }
    short8 a[2], bb[2];
#pragma unroll
    for (int mi = 0; mi < 2; ++mi)
      a[mi] = *reinterpret_cast<const short8*>(
          &As[cur][(wm * 32 + mi * 16 + fr) * 32 + fq * 8]);
#pragma unroll
    for (int ni = 0; ni < 2; ++ni)
      bb[ni] = *reinterpret_cast<const short8*>(
          &Bs[cur][(wn * 32 + ni * 16 + fr) * 32 + fq * 8]);
#pragma unroll
    for (int mi = 0; mi < 2; ++mi)
#pragma unroll
      for (int ni = 0; ni < 2; ++ni)
        acc[mi][ni] = __builtin_amdgcn_mfma_f32_16x16x32_bf16(
            a[mi], bb[ni], acc[mi][ni], 0, 0, 0);
    __syncthreads();
  }

  float bsv[2];
#pragma unroll
  for (int ni = 0; ni < 2; ++ni) bsv[ni] = bias[e_base + wn * 32 + ni * 16 + fr];

  if (MODE == 1) {
#pragma unroll
    for (int mi = 0; mi < 2; ++mi)
#pragma unroll
      for (int t4 = 0; t4 < 4; ++t4) {
        int m = m_base + wm * 32 + mi * 16 + fq * 4 + t4;
#pragma unroll
        for (int ni = 0; ni < 2; ++ni) {
          int e = e_base + wn * 32 + ni * 16 + fr;
          float v = acc[mi][ni][t4] + bsv[ni];
          v = v > 0.0f ? v : expm1f(v);
          fOut[(size_t)m * DD + e] = v;
        }
      }
  } else {
    int b = m_base >> 9, j0 = m_base & (NN - 1);
    ushort* LT = &As[0][0];  // reuse as [64][68] (4352 <= 8192 ushorts)
    ushort hv[2][2][4];
#pragma unroll
    for (int mi = 0; mi < 2; ++mi)
#pragma unroll
      for (int ni = 0; ni < 2; ++ni)
#pragma unroll
        for (int t4 = 0; t4 < 4; ++t4) {
          int m = m_base + wm * 32 + mi * 16 + fq * 4 + t4;
          int e = e_base + wn * 32 + ni * 16 + fr;
          float v = acc[mi][ni][t4] + bsv[ni];
          v = v > 0.0f ? v : expm1f(v);
          ushort u = f2bf(v);
          hOut[(size_t)m * KCAT + e] = u;
          hv[mi][ni][t4] = u;
        }
    // transpose through LDS (loop-end barrier already separated ds_reads)
#pragma unroll
    for (int mi = 0; mi < 2; ++mi)
#pragma unroll
      for (int ni = 0; ni < 2; ++ni)
#pragma unroll
        for (int t4 = 0; t4 < 4; ++t4) {
          int ml = wm * 32 + mi * 16 + fq * 4 + t4;
          int el = wn * 32 + ni * 16 + fr;
          LT[el * 68 + ml] = hv[mi][ni][t4];
        }
    __syncthreads();
    int er = t >> 2, mq = (t & 3) * 16;
    ushort* dst = hT + ((size_t)(b * DD + e_base + er)) * NN + j0 + mq;
    int4 v0 = *reinterpret_cast<const int4*>(&LT[er * 68 + mq]);
    int4 v1 = *reinterpret_cast<const int4*>(&LT[er * 68 + mq + 8]);
    *reinterpret_cast<int4*>(dst) = v0;
    *reinterpret_cast<int4*>(dst + 8) = v1;
  }
}

extern "C" void kernel_launch(void* const* d_in, const int* in_sizes, int n_in,
                              void* d_out, int out_size, void* d_ws,
                              size_t ws_size, hipStream_t stream) {
  const float* x = (const float*)d_in[0];
  const float* w_rel1 = (const float*)d_in[1];
  const float* w_root1 = (const float*)d_in[2];
  const float* b1 = (const float*)d_in[3];
  const float* w_rel2 = (const float*)d_in[4];
  const float* w_root2 = (const float*)d_in[5];
  const float* b2 = (const float*)d_in[6];
  const int* aug = (const int*)d_in[7];
  const int* punct = (const int*)d_in[8];
  float* out = (float*)d_out;

  char* ws = (char*)d_ws;
  size_t off = 0;
  unsigned long long* bitsT = (unsigned long long*)(ws + off); off += (size_t)RR * BS * NN * 8 * 8;
  float* inv_deg = (float*)(ws + off);                         off += (size_t)RR * BS * NN * 4;
  ushort* MT = (ushort*)(ws + off);                            off += (size_t)RR * BS * NN * NN * 2;
  ushort* xT = (ushort*)(ws + off);                            off += (size_t)BS * DD * NN * 2;
  ushort* hT = (ushort*)(ws + off);                            off += (size_t)BS * DD * NN * 2;
  ushort* WcatT1 = (ushort*)(ws + off);                        off += (size_t)DD * KCAT * 2;
  ushort* WcatT2 = (ushort*)(ws + off);                        off += (size_t)DD * KCAT * 2;
  ushort* Abig1 = (ushort*)(ws + off);                         off += (size_t)M_TOT * KCAT * 2;
  ushort* Abig2 = (ushort*)(ws + off);                         off += (size_t)M_TOT * KCAT * 2;

  masks_kernel<<<dim3(2, 8, 16), 256, 0, stream>>>(aug, punct, bitsT);
  mt_kernel<<<dim3(NN, BS), 256, 0, stream>>>(bitsT, MT, inv_deg);
  xprep_kernel<<<dim3(16, 8, 16), dim3(32, 8), 0, stream>>>(x, Abig1, xT);
  wcat_kernel<<<dim3(8, 8, 6), dim3(32, 8), 0, stream>>>(w_root1, w_rel1,
                                                         w_root2, w_rel2,
                                                         WcatT1, WcatT2);

  // layer 1
  agg_gemm_kernel<<<dim3(4, 4, 32), 256, 0, stream>>>(MT, xT, inv_deg, Abig1);
  main_gemm_kernel<0><<<dim3(4, 128), 256, 0, stream>>>(Abig1, WcatT1, b1,
                                                        Abig2, hT, nullptr);
  // layer 2
  agg_gemm_kernel<<<dim3(4, 4, 32), 256, 0, stream>>>(MT, hT, inv_deg, Abig2);
  main_gemm_kernel<1><<<dim3(4, 128), 256, 0, stream>>>(Abig2, WcatT2, b2,
                                                        nullptr, nullptr, out);
}